// Round 9
// baseline (50.598 us; speedup 1.0000x reference)
//
#include <hip/hip_runtime.h>

// x[2][4][128][128][128] f32, y[2][1][128][128][128] int32
constexpr int SPB = 1 << 21;
constexpr float EPSV = 1e-6f;

// Static scratch: packed per-voxel mask, 4 MB.
// mask[v] = (center_class << 4) | OR_{3x3x3 clipped}(1 << y[v+d])
__device__ unsigned char g_mask[2 * SPB];

// ===========================================================================
// K0: build packed 27-neighborhood presence mask + center class (proven R5)
// ===========================================================================
constexpr int K0_ZSEG = 4;
constexpr int K0_NBLK = (2 * (128 / K0_ZSEG) * 128) / 4;  // 2048

struct MEnt { int pk, cx, cy; };

__device__ __forceinline__ MEnt k0_load(const int* __restrict__ yb, int s,
                                        int rbase0, bool ym1, bool yp1) {
    MEnt e;
    const int rb = (s << 14) | rbase0;
    int2 vc = *(const int2*)(yb + rb);
    int nib0 = 1 << vc.x, nib1 = 1 << vc.y;
    if (ym1) { int2 vm = *(const int2*)(yb + rb - 128); nib0 |= 1 << vm.x; nib1 |= 1 << vm.y; }
    if (yp1) { int2 vp = *(const int2*)(yb + rb + 128); nib0 |= 1 << vp.x; nib1 |= 1 << vp.y; }
    e.pk = nib0 | (nib1 << 8);
    e.cx = vc.x; e.cy = vc.y;
    return e;
}

__global__ __launch_bounds__(256) void mask_build(const int* __restrict__ y32) {
    const int wid = (blockIdx.x << 2) | (threadIdx.x >> 6);
    const int lane = threadIdx.x & 63;
    const int yy = wid & 127;
    const int zs = (wid >> 7) & 31;
    const int b = (wid >> 12) & 1;
    const int x0 = lane << 1;
    const int z0 = zs * K0_ZSEG;
    const bool ym1 = yy > 0, yp1 = yy < 127;
    const int rbase0 = (yy << 7) | x0;

    const int* __restrict__ yb = y32 + ((long)b << 21);
    unsigned char* __restrict__ mb = g_mask + ((long)b << 21);

    MEnt e0, e1;
    if (z0 > 0) e0 = k0_load(yb, z0 - 1, rbase0, ym1, yp1);
    else { e0.pk = 0; e0.cx = 0; e0.cy = 0; }
    e1 = k0_load(yb, z0, rbase0, ym1, yp1);

#pragma unroll
    for (int dz = 0; dz < K0_ZSEG; ++dz) {
        const int z = z0 + dz;
        MEnt e2;
        if (z + 1 < 128) e2 = k0_load(yb, z + 1, rbase0, ym1, yp1);
        else { e2.pk = 0; e2.cx = 0; e2.cy = 0; }

        const int zor = e0.pk | e1.pk | e2.pk;
        int orL = __shfl_up(zor, 1);
        if (lane == 0) orL = 0;
        int orR = __shfl_down(zor, 1);
        if (lane == 63) orR = 0;
        const int full0 = (zor | (zor >> 8) | (orL >> 8)) & 15;
        const int full1 = (zor | (zor >> 8) | orR) & 15;

        const unsigned short st =
            (unsigned short)((full0 | (e1.cx << 4)) | ((full1 | (e1.cy << 4)) << 8));
        *(unsigned short*)(mb + ((z << 14) | rbase0)) = st;

        e0 = e1; e1 = e2;
    }
}

// ===========================================================================
// K1: LDS-staged block stencil, register y-product ring.
// Block = (plane, 8 rows, all x, 8 z-slices). LDS: ring-of-3 raw slices only
// (15.4 KB). One barrier per z-step. 2048 blocks -> 8 blocks/CU (32 waves).
// ===========================================================================
constexpr int ZC = 8;                          // output slices per block
constexpr int NBLK = 8 * 16 * (128 / ZC);      // 2048

__global__ __launch_bounds__(256) void lah_main(const float* __restrict__ x,
                                                float* __restrict__ acc) {
    __shared__ float raw[3][10][128];   // raw x, rows r0-1 .. r0+8
    __shared__ float sred[4];

    const int bid = blockIdx.x;
    const int plane = bid & 7;            // -> XCD (round-robin dispatch)
    const int b = plane >> 2, cls = plane & 3;
    const int inner = bid >> 3;           // 0..255
    const int yc = inner & 15;
    const int zq = inner >> 4;            // 0..15
    const int r0 = yc * 8;
    const int z0 = zq * ZC;
    const int t = threadIdx.x;
    const int rr = t >> 5;                // 0..7 (center-row index)
    const int xc = (t & 31) << 2;         // 0,4,...,124
    const int lane = t & 63;

    const float* __restrict__ xp = x + ((long)plane << 21);
    const unsigned char* __restrict__ mb = g_mask + ((long)b << 21);
    const int mrow = (r0 + rr) << 7;

    // load float4 of global slice k, local row i (0..9); OOB -> zeros (neutral)
    auto gload = [&](int k, int i) -> float4 {
        const int gr = r0 - 1 + i;
        if ((unsigned)k > 127u || (unsigned)gr > 127u)
            return make_float4(0.f, 0.f, 0.f, 0.f);
        return *(const float4*)(xp + ((k << 14) | (gr << 7) | xc));
    };
    auto stage_direct = [&](int k, int s) {
        *(float4*)&raw[s][rr][xc] = gload(k, rr);
        if (t < 64) *(float4*)&raw[s][8 + (t >> 5)][xc] = gload(k, 8 + (t >> 5));
    };
    // y-product of (1-x) over rows rr-1..rr+1 of buffer s; center raw -> cx
    auto yprod = [&](int s, float4& cx) -> float4 {
        const float4 a = *(const float4*)&raw[s][rr][xc];
        const float4 bq = *(const float4*)&raw[s][rr + 1][xc];
        const float4 c = *(const float4*)&raw[s][rr + 2][xc];
        cx = bq;
        float4 o;
        o.x = (1.f - a.x) * (1.f - bq.x) * (1.f - c.x);
        o.y = (1.f - a.y) * (1.f - bq.y) * (1.f - c.y);
        o.z = (1.f - a.z) * (1.f - bq.z) * (1.f - c.z);
        o.w = (1.f - a.w) * (1.f - bq.w) * (1.f - c.w);
        return o;
    };

    // ---- prologue: stage slices z0-1, z0, z0+1 into slots 0,1,2 ----
    stage_direct(z0 - 1, 0);
    stage_direct(z0, 1);
    stage_direct(z0 + 1, 2);
    __syncthreads();
    float4 cxd, cx0;
    float4 ypm1 = yprod(0, cxd);
    float4 yp0 = yprod(1, cx0);
    unsigned mcur = *(const unsigned*)(mb + ((z0 << 14) | mrow | xc));

    int sm = 0, s0 = 1, sp = 2;  // ring slots for slices z-1, z, z+1

    float fp = 0.f, fn = 0.f, sx = 0.f, sy = 0.f;

#pragma unroll
    for (int dz = 0; dz < ZC; ++dz) {
        const int z = z0 + dz;
        __syncthreads();  // makes prev iter's slot write visible; guards slot reuse

        // Phase 1: prefetch slice z+2 into regs; mask row of slice z+1
        float4 gA = make_float4(0.f, 0.f, 0.f, 0.f);
        float4 gB = make_float4(0.f, 0.f, 0.f, 0.f);
        unsigned mnext = 0;
        if (dz < ZC - 1) {
            gA = gload(z + 2, rr);
            if (t < 64) gB = gload(z + 2, 8 + (t >> 5));
            mnext = *(const unsigned*)(mb + (((z + 1) << 14) | mrow | xc));
        }

        // Phase 2: y-products of slice z+1 from LDS (register ring fill)
        float4 cx1;
        const float4 ypp1 = yprod(sp, cx1);

        // Phase 3: compute voxels of slice z (registers only)
        {
            const float zp0 = ypm1.x * yp0.x * ypp1.x;
            const float zp1 = ypm1.y * yp0.y * ypp1.y;
            const float zp2 = ypm1.z * yp0.z * ypp1.z;
            const float zp3 = ypm1.w * yp0.w * ypp1.w;
            float zl = __shfl_up(zp3, 1);
            if ((t & 31) == 0) zl = 1.f;
            float zr = __shfl_down(zp0, 1);
            if ((t & 31) == 31) zr = 1.f;
            const float t01 = zp0 * zp1, t12 = zp1 * zp2, t23 = zp2 * zp3;
            const float P[4] = {zl * t01, t01 * zp2, t12 * zp3, t23 * zr};
            const float xa[4] = {cx0.x, cx0.y, cx0.z, cx0.w};
#pragma unroll
            for (int j = 0; j < 4; ++j) {
                const int m = (mcur >> (j * 8)) & 0xFF;
                const bool pres = (m >> cls) & 1;
                const bool eq = (m >> 4) == cls;
                const float xv = xa[j];
                sx += xv;
                fp += eq ? 0.f : xv * (pres ? 1.f : 2.f);
                fn += eq ? (1.f - xv) * (1.f + P[j]) : 0.f;
                sy += eq ? 1.f : 0.f;
            }
        }

        // Phase 4: write prefetched slice z+2 into the retiring slot (z-1)
        if (dz < ZC - 1) {
            *(float4*)&raw[sm][rr][xc] = gA;
            if (t < 64) *(float4*)&raw[sm][8 + (t >> 5)][xc] = gB;
        }

        // rotate slot ring and register rings
        const int tmp = sm; sm = s0; s0 = sp; sp = tmp;
        ypm1 = yp0; yp0 = ypp1; cx0 = cx1; mcur = mnext;
    }

    // ---- reduce 4 scalars: wave shuffle -> block LDS -> global atomics ----
    float rr4[4] = {fp, fn, sx, sy};
#pragma unroll
    for (int i = 0; i < 4; ++i) {
        float vv = rr4[i];
#pragma unroll
        for (int off = 32; off >= 1; off >>= 1) vv += __shfl_down(vv, off);
        rr4[i] = vv;
    }
    if (t < 4) sred[t] = 0.f;
    __syncthreads();
    if (lane == 0) {
#pragma unroll
        for (int i = 0; i < 4; ++i) atomicAdd(&sred[i], rr4[i]);
    }
    __syncthreads();
    if (t < 4)
        atomicAdd(&acc[b * 16 + t * 4 + cls], sred[t]);
}

// ===========================================================================
// K2: finalize scalar loss
// ===========================================================================
__global__ void lah_finalize(const float* __restrict__ acc, float* __restrict__ out) {
    float loss = 0.f;
#pragma unroll
    for (int b = 0; b < 2; ++b) {
#pragma unroll
        for (int c = 1; c < 4; ++c) {
            const float fp = acc[b * 16 + 0 + c];
            const float fn = acc[b * 16 + 4 + c];
            const float sxv = acc[b * 16 + 8 + c];
            const float syv = acc[b * 16 + 12 + c];
            loss += fmaxf(fp / (sxv + EPSV), fn / (syv + EPSV));
        }
    }
    out[0] = loss / 6.f;
}

extern "C" void kernel_launch(void* const* d_in, const int* in_sizes, int n_in,
                              void* d_out, int out_size, void* d_ws, size_t ws_size,
                              hipStream_t stream) {
    const float* x = (const float*)d_in[0];
    const int* y32 = (const int*)d_in[1];
    float* out = (float*)d_out;
    float* acc = (float*)d_ws;  // 32 floats

    hipMemsetAsync(d_ws, 0, 32 * sizeof(float), stream);
    mask_build<<<K0_NBLK, 256, 0, stream>>>(y32);
    lah_main<<<NBLK, 256, 0, stream>>>(x, acc);
    lah_finalize<<<1, 1, 0, stream>>>(acc, out);
}

// Round 10
// 49.218 us; speedup vs baseline: 1.0280x; 1.0280x over previous
//
#include <hip/hip_runtime.h>

// x[2][4][128][128][128] f32, y[2][1][128][128][128] int32
constexpr int SPB = 1 << 21;
constexpr float EPSV = 1e-6f;

// Static scratch: packed per-voxel mask, 4 MB.
// mask[v] = (center_class << 4) | OR_{3x3x3 clipped}(1 << y[v+d])
__device__ unsigned char g_mask[2 * SPB];

// ===========================================================================
// K0: build packed 27-neighborhood presence mask + center class (proven R5)
// ===========================================================================
constexpr int K0_ZSEG = 4;
constexpr int K0_NBLK = (2 * (128 / K0_ZSEG) * 128) / 4;  // 2048

struct MEnt { int pk, cx, cy; };

__device__ __forceinline__ MEnt k0_load(const int* __restrict__ yb, int s,
                                        int rbase0, bool ym1, bool yp1) {
    MEnt e;
    const int rb = (s << 14) | rbase0;
    int2 vc = *(const int2*)(yb + rb);
    int nib0 = 1 << vc.x, nib1 = 1 << vc.y;
    if (ym1) { int2 vm = *(const int2*)(yb + rb - 128); nib0 |= 1 << vm.x; nib1 |= 1 << vm.y; }
    if (yp1) { int2 vp = *(const int2*)(yb + rb + 128); nib0 |= 1 << vp.x; nib1 |= 1 << vp.y; }
    e.pk = nib0 | (nib1 << 8);
    e.cx = vc.x; e.cy = vc.y;
    return e;
}

__global__ __launch_bounds__(256) void mask_build(const int* __restrict__ y32) {
    const int wid = (blockIdx.x << 2) | (threadIdx.x >> 6);
    const int lane = threadIdx.x & 63;
    const int yy = wid & 127;
    const int zs = (wid >> 7) & 31;
    const int b = (wid >> 12) & 1;
    const int x0 = lane << 1;
    const int z0 = zs * K0_ZSEG;
    const bool ym1 = yy > 0, yp1 = yy < 127;
    const int rbase0 = (yy << 7) | x0;

    const int* __restrict__ yb = y32 + ((long)b << 21);
    unsigned char* __restrict__ mb = g_mask + ((long)b << 21);

    MEnt e0, e1;
    if (z0 > 0) e0 = k0_load(yb, z0 - 1, rbase0, ym1, yp1);
    else { e0.pk = 0; e0.cx = 0; e0.cy = 0; }
    e1 = k0_load(yb, z0, rbase0, ym1, yp1);

#pragma unroll
    for (int dz = 0; dz < K0_ZSEG; ++dz) {
        const int z = z0 + dz;
        MEnt e2;
        if (z + 1 < 128) e2 = k0_load(yb, z + 1, rbase0, ym1, yp1);
        else { e2.pk = 0; e2.cx = 0; e2.cy = 0; }

        const int zor = e0.pk | e1.pk | e2.pk;
        int orL = __shfl_up(zor, 1);
        if (lane == 0) orL = 0;
        int orR = __shfl_down(zor, 1);
        if (lane == 63) orR = 0;
        const int full0 = (zor | (zor >> 8) | (orL >> 8)) & 15;
        const int full1 = (zor | (zor >> 8) | orR) & 15;

        const unsigned short st =
            (unsigned short)((full0 | (e1.cx << 4)) | ((full1 | (e1.cy << 4)) << 8));
        *(unsigned short*)(mb + ((z << 14) | rbase0)) = st;

        e0 = e1; e1 = e2;
    }
}

// ===========================================================================
// K1: LDS-staged block stencil, ring-of-4 slots, DISTANCE-2 global prefetch.
// Block = (plane, 8 rows, all x, 8 z-slices). The ds_write of slice z+2 waits
// (counted vmcnt) on loads issued a FULL iteration earlier; loads for z+3
// stay in flight across the barrier. One barrier per z-step.
// ===========================================================================
constexpr int ZC = 8;                          // output slices per block
constexpr int NBLK = 8 * 16 * (128 / ZC);      // 2048

__global__ __launch_bounds__(256) void lah_main(const float* __restrict__ x,
                                                float* __restrict__ acc) {
    __shared__ float raw[4][10][128];   // 20.5 KB: slices (s & 3), rows r0-1..r0+8
    __shared__ float sred[4];

    const int bid = blockIdx.x;
    const int plane = bid & 7;            // -> XCD (round-robin dispatch)
    const int b = plane >> 2, cls = plane & 3;
    const int inner = bid >> 3;           // 0..255
    const int yc = inner & 15;
    const int zq = inner >> 4;            // 0..15
    const int r0 = yc * 8;
    const int z0 = zq * ZC;               // multiple of 8 -> z0 & 3 == 0
    const int t = threadIdx.x;
    const int rr = t >> 5;                // 0..7 (center-row index)
    const int xc = (t & 31) << 2;         // 0,4,...,124
    const int lane = t & 63;
    const int xrow = 8 + (t >> 5);        // only used when t < 64 -> rows 8,9

    const float* __restrict__ xp = x + ((long)plane << 21);
    const unsigned char* __restrict__ mb = g_mask + ((long)b << 21);
    const int mrow = (r0 + rr) << 7;

    const float4 Z4 = make_float4(0.f, 0.f, 0.f, 0.f);

    // load float4 of global slice k, local row i (0..9); OOB -> zeros (neutral)
    auto gload = [&](int k, int i) -> float4 {
        const int gr = r0 - 1 + i;
        if ((unsigned)k > 127u || (unsigned)gr > 127u)
            return make_float4(0.f, 0.f, 0.f, 0.f);
        return *(const float4*)(xp + ((k << 14) | (gr << 7) | xc));
    };
    auto stage_direct = [&](int k) {
        const int s = k & 3;
        *(float4*)&raw[s][rr][xc] = gload(k, rr);
        if (t < 64) *(float4*)&raw[s][xrow][xc] = gload(k, xrow);
    };
    // y-product of (1-x) over rows rr-1..rr+1 of slot s; center raw row -> cx
    auto yprod = [&](int s, float4& cx) -> float4 {
        const float4 a = *(const float4*)&raw[s][rr][xc];
        const float4 bq = *(const float4*)&raw[s][rr + 1][xc];
        const float4 c = *(const float4*)&raw[s][rr + 2][xc];
        cx = bq;
        float4 o;
        o.x = (1.f - a.x) * (1.f - bq.x) * (1.f - c.x);
        o.y = (1.f - a.y) * (1.f - bq.y) * (1.f - c.y);
        o.z = (1.f - a.z) * (1.f - bq.z) * (1.f - c.z);
        o.w = (1.f - a.w) * (1.f - bq.w) * (1.f - c.w);
        return o;
    };

    // ---- prologue: stage z0-1, z0, z0+1; pend loads for z0+2 ----
    stage_direct(z0 - 1);
    stage_direct(z0);
    stage_direct(z0 + 1);
    float4 pA = gload(z0 + 2, rr);
    float4 pB = (t < 64) ? gload(z0 + 2, xrow) : Z4;
    __syncthreads();
    float4 cxd, cx0;
    float4 ypm1 = yprod((z0 - 1) & 3, cxd);
    float4 yp0 = yprod(z0 & 3, cx0);
    unsigned mcur = *(const unsigned*)(mb + ((z0 << 14) | mrow | xc));

    float fp = 0.f, fn = 0.f, sx = 0.f, sy = 0.f;

#pragma unroll
    for (int dz = 0; dz < ZC; ++dz) {
        const int z = z0 + dz;

        // Phase 1: issue NEXT prefetch (slice z+3) + mask row of slice z+1.
        float4 nA = Z4, nB = Z4;
        if (dz <= ZC - 3) {
            nA = gload(z + 3, rr);
            if (t < 64) nB = gload(z + 3, xrow);
        }
        unsigned mnext = 0;
        if (dz <= ZC - 2)
            mnext = *(const unsigned*)(mb + (((z + 1) << 14) | mrow | xc));

        // Phase 2: y-products of slice z+1 from LDS (register ring fill)
        float4 cx1;
        const float4 ypp1 = yprod((z + 1) & 3, cx1);

        // Phase 3: compute voxels of slice z (registers only)
        {
            const float zp0 = ypm1.x * yp0.x * ypp1.x;
            const float zp1 = ypm1.y * yp0.y * ypp1.y;
            const float zp2 = ypm1.z * yp0.z * ypp1.z;
            const float zp3 = ypm1.w * yp0.w * ypp1.w;
            float zl = __shfl_up(zp3, 1);
            if ((t & 31) == 0) zl = 1.f;
            float zr = __shfl_down(zp0, 1);
            if ((t & 31) == 31) zr = 1.f;
            const float t01 = zp0 * zp1, t12 = zp1 * zp2, t23 = zp2 * zp3;
            const float P[4] = {zl * t01, t01 * zp2, t12 * zp3, t23 * zr};
            const float xa[4] = {cx0.x, cx0.y, cx0.z, cx0.w};
#pragma unroll
            for (int j = 0; j < 4; ++j) {
                const int m = (mcur >> (j * 8)) & 0xFF;
                const bool pres = (m >> cls) & 1;
                const bool eq = (m >> 4) == cls;
                const float xv = xa[j];
                sx += xv;
                fp += eq ? 0.f : xv * (pres ? 1.f : 2.f);
                fn += eq ? (1.f - xv) * (1.f + P[j]) : 0.f;
                sy += eq ? 1.f : 0.f;
            }
        }

        // Phase 4: write PREVIOUS pend (slice z+2) into its slot.
        // vmcnt here is counted: waits only on pA/pB (issued last iteration),
        // nA/nB (just issued) remain in flight across the barrier.
        if (dz <= ZC - 2) {
            const int s = (z + 2) & 3;
            *(float4*)&raw[s][rr][xc] = pA;
            if (t < 64) *(float4*)&raw[s][xrow][xc] = pB;
        }
        __syncthreads();

        // rotate register rings
        pA = nA; pB = nB;
        ypm1 = yp0; yp0 = ypp1; cx0 = cx1; mcur = mnext;
    }

    // ---- reduce 4 scalars: wave shuffle -> block LDS -> global atomics ----
    float rr4[4] = {fp, fn, sx, sy};
#pragma unroll
    for (int i = 0; i < 4; ++i) {
        float vv = rr4[i];
#pragma unroll
        for (int off = 32; off >= 1; off >>= 1) vv += __shfl_down(vv, off);
        rr4[i] = vv;
    }
    if (t < 4) sred[t] = 0.f;
    __syncthreads();
    if (lane == 0) {
#pragma unroll
        for (int i = 0; i < 4; ++i) atomicAdd(&sred[i], rr4[i]);
    }
    __syncthreads();
    if (t < 4)
        atomicAdd(&acc[b * 16 + t * 4 + cls], sred[t]);
}

// ===========================================================================
// K2: finalize scalar loss
// ===========================================================================
__global__ void lah_finalize(const float* __restrict__ acc, float* __restrict__ out) {
    float loss = 0.f;
#pragma unroll
    for (int b = 0; b < 2; ++b) {
#pragma unroll
        for (int c = 1; c < 4; ++c) {
            const float fp = acc[b * 16 + 0 + c];
            const float fn = acc[b * 16 + 4 + c];
            const float sxv = acc[b * 16 + 8 + c];
            const float syv = acc[b * 16 + 12 + c];
            loss += fmaxf(fp / (sxv + EPSV), fn / (syv + EPSV));
        }
    }
    out[0] = loss / 6.f;
}

extern "C" void kernel_launch(void* const* d_in, const int* in_sizes, int n_in,
                              void* d_out, int out_size, void* d_ws, size_t ws_size,
                              hipStream_t stream) {
    const float* x = (const float*)d_in[0];
    const int* y32 = (const int*)d_in[1];
    float* out = (float*)d_out;
    float* acc = (float*)d_ws;  // 32 floats

    hipMemsetAsync(d_ws, 0, 32 * sizeof(float), stream);
    mask_build<<<K0_NBLK, 256, 0, stream>>>(y32);
    lah_main<<<NBLK, 256, 0, stream>>>(x, acc);
    lah_finalize<<<1, 1, 0, stream>>>(acc, out);
}